// Round 1
// baseline (116.270 us; speedup 1.0000x reference)
//
#include <hip/hip_runtime.h>

#define BB 8
#define LL 2048
#define DD 64
#define CC 64
#define NCH (LL/CC)   // 32 chunks per stream

typedef float f32x2 __attribute__((ext_vector_type(2)));

// workspace layout (float offsets)
#define OFF_PREF 0
#define SZ_PREF (BB*NCH*8192)                 // per-(s,c): A(4096) then K(4096)
#define OFF_KAP (OFF_PREF + SZ_PREF)          // kappa[s*L+t] = ||k_t||^2
#define OFF_NU  (OFF_KAP + BB*LL)             // nu[s*L+t]    = ||v_t||^2
#define OFF_T0  (OFF_NU + BB*LL)              // per-(s,c): {T0, s0}
#define OFF_OUTP (OFF_T0 + BB*NCH*2)          // per-lane output partials [s*L+t][64]

static __device__ __forceinline__ f32x2 pkfma(f32x2 a, f32x2 b, f32x2 c) {
  return __builtin_elementwise_fma(a, b, c);
}

// K0: per-token kappa = ||k||^2, nu = ||v||^2  (one wave per token)
__global__ __launch_bounds__(256) void k0_kapnu(const float* __restrict__ k,
                                                const float* __restrict__ v,
                                                float* __restrict__ ws) {
  int wid = (blockIdx.x * 256 + threadIdx.x) >> 6;
  int lane = threadIdx.x & 63;
  float kk = k[(size_t)wid * 64 + lane];
  float vv = v[(size_t)wid * 64 + lane];
  float pk = kk * kk, pv = vv * vv;
  #pragma unroll
  for (int m = 1; m < 64; m <<= 1) {
    pk += __shfl_xor(pk, m, 64);
    pv += __shfl_xor(pv, m, 64);
  }
  if (lane == 0) {
    ws[OFF_KAP + wid] = pk;
    ws[OFF_NU + wid] = pv;
  }
}

// K1: per-chunk partial sums of v k^T and k k^T. 4 waves, wave w owns cols [16w,16w+16).
__global__ __launch_bounds__(256) void k1_partial(const float* __restrict__ k,
                                                  const float* __restrict__ v,
                                                  float* __restrict__ ws) {
  int s = blockIdx.x / NCH, c = blockIdx.x % NCH;
  int tid = threadIdx.x;
  int lane = tid & 63;
  int j0 = __builtin_amdgcn_readfirstlane((tid >> 6) * 16);
  const float* kb = k + (size_t)(s * LL + c * CC) * 64;
  const float* vb = v + (size_t)(s * LL + c * CC) * 64;
  f32x2 accA[8] = {}, accK[8] = {};
  for (int t = 0; t < CC; ++t) {
    const float* kr = kb + t * 64;
    float vl = vb[t * 64 + lane];
    float kl = kr[lane];
    f32x2 vl2 = {vl, vl}, kl2 = {kl, kl};
    #pragma unroll
    for (int e = 0; e < 8; ++e) {
      f32x2 sk = *(const f32x2*)(kr + j0 + 2 * e);
      accA[e] = pkfma(vl2, sk, accA[e]);
      accK[e] = pkfma(kl2, sk, accK[e]);
    }
  }
  float* dst = ws + OFF_PREF + (size_t)(s * NCH + c) * 8192;
  #pragma unroll
  for (int e = 0; e < 8; ++e) {
    *(f32x2*)(dst + lane * 64 + j0 + 2 * e) = accA[e];
    *(f32x2*)(dst + 4096 + lane * 64 + j0 + 2 * e) = accK[e];
  }
}

// K2: in-place exclusive prefix over chunks for each state element
__global__ __launch_bounds__(256) void k2_prefix(float* __restrict__ ws) {
  int gid = blockIdx.x * 256 + threadIdx.x;   // [0, BB*8192)
  int s = gid >> 13, e = gid & 8191;
  float* base = ws + OFF_PREF + (size_t)s * NCH * 8192 + e;
  float acc = 0.f;
  #pragma unroll 4
  for (int c = 0; c < NCH; ++c) {
    float x = base[(size_t)c * 8192];
    base[(size_t)c * 8192] = acc;
    acc += x;
  }
}

// K2b: per-(s,c) chunk-start scalars T0 = Tr(A0 K0 A0^T), s0 = sum of nu before chunk
__global__ __launch_bounds__(256) void k2b_t0(float* __restrict__ ws) {
  int s = blockIdx.x / NCH, c = blockIdx.x % NCH;
  int tid = threadIdx.x, lane = tid & 63;
  int j0 = __builtin_amdgcn_readfirstlane((tid >> 6) * 16);
  const float* pref = ws + OFF_PREF + (size_t)(s * NCH + c) * 8192;
  // A0 row `lane` into regs
  f32x2 Ar[32];
  #pragma unroll
  for (int j = 0; j < 32; ++j) Ar[j] = *(const f32x2*)(pref + lane * 64 + 2 * j);
  // acc[j] = sum_m A0[i][m] * K0[m][j0+2j..]
  f32x2 acc[8] = {};
  #pragma unroll
  for (int m = 0; m < 64; ++m) {
    float am = (m & 1) ? Ar[m >> 1].y : Ar[m >> 1].x;
    f32x2 am2 = {am, am};
    const float* krow = pref + 4096 + m * 64 + j0;   // wave-uniform
    #pragma unroll
    for (int e = 0; e < 8; ++e)
      acc[e] = pkfma(am2, *(const f32x2*)(krow + 2 * e), acc[e]);
  }
  // t0 partial = sum_j acc[j] * A0[i][j0+...]
  f32x2 tp2 = {0, 0};
  #pragma unroll
  for (int e = 0; e < 8; ++e) {
    f32x2 arr = *(const f32x2*)(pref + lane * 64 + j0 + 2 * e);
    tp2 = pkfma(acc[e], arr, tp2);
  }
  float t0p = tp2.x + tp2.y;
  // s0 partial
  float s0p = 0.f;
  const float* nub = ws + OFF_NU + s * LL;
  for (int t = tid; t < c * CC; t += 256) s0p += nub[t];
  #pragma unroll
  for (int m = 1; m < 64; m <<= 1) {
    t0p += __shfl_xor(t0p, m, 64);
    s0p += __shfl_xor(s0p, m, 64);
  }
  __shared__ float red[8];
  if (lane == 0) { red[(tid >> 6) * 2] = t0p; red[(tid >> 6) * 2 + 1] = s0p; }
  __syncthreads();
  if (tid == 0) {
    ws[OFF_T0 + (s * NCH + c) * 2]     = red[0] + red[2] + red[4] + red[6];
    ws[OFF_T0 + (s * NCH + c) * 2 + 1] = red[1] + red[3] + red[5] + red[7];
  }
}

// K3: the sequential scan over one 64-token chunk. One wave; lane i owns row i of A and K.
__global__ __launch_bounds__(64, 1) void k3_scan(const float* __restrict__ k,
                                                 const float* __restrict__ v,
                                                 float* __restrict__ ws) {
  int s = blockIdx.x / NCH, c = blockIdx.x % NCH;
  int lane = threadIdx.x;
  const float* pref = ws + OFF_PREF + (size_t)(s * NCH + c) * 8192;
  f32x2 A[32], Kr[32];
  #pragma unroll
  for (int j = 0; j < 32; ++j) A[j] = *(const f32x2*)(pref + lane * 64 + 2 * j);
  #pragma unroll
  for (int j = 0; j < 32; ++j) Kr[j] = *(const f32x2*)(pref + 4096 + lane * 64 + 2 * j);
  // per-lane ||A0 row||^2 (sums to F0 across lanes)
  f32x2 f2 = {0, 0};
  #pragma unroll
  for (int j = 0; j < 32; ++j) f2 = pkfma(A[j], A[j], f2);
  float pF = f2.x + f2.y;
  float T0 = ws[OFF_T0 + (s * NCH + c) * 2];
  float S0 = ws[OFF_T0 + (s * NCH + c) * 2 + 1];
  float m0 = (lane == 0) ? 1.f : 0.f;
  float pT = m0 * T0;
  float pS = m0 * S0;
  const float* kb  = k + (size_t)(s * LL + c * CC) * 64;
  const float* vb  = v + (size_t)(s * LL + c * CC) * 64;
  const float* kap = ws + OFF_KAP + s * LL + c * CC;
  const float* nuv = ws + OFF_NU  + s * LL + c * CC;
  float* op = ws + OFF_OUTP + (size_t)(s * LL + c * CC) * 64 + lane;
  __shared__ float bbuf[128];

  for (int t = 0; t < CC; ++t) {
    const float* kr = kb + t * 64;
    float kl = kr[lane];
    float vl = vb[t * 64 + lane];
    float ka = kap[t], nv = nuv[t];
    // k_t broadcast (wave-uniform -> SGPRs)
    f32x2 sk[32];
    #pragma unroll
    for (int j = 0; j < 32; ++j) sk[j] = *(const f32x2*)(kr + 2 * j);
    // b = K' k
    f32x2 b0 = {0,0}, b1 = {0,0}, b2 = {0,0}, b3 = {0,0};
    #pragma unroll
    for (int j = 0; j < 8; ++j) {
      b0 = pkfma(Kr[j],      sk[j],      b0);
      b1 = pkfma(Kr[j + 8],  sk[j + 8],  b1);
      b2 = pkfma(Kr[j + 16], sk[j + 16], b2);
      b3 = pkfma(Kr[j + 24], sk[j + 24], b3);
    }
    b0 += b1; b2 += b3; b0 += b2;
    float bi = b0.x + b0.y;
    bbuf[((t & 1) << 6) + lane] = bi;
    // a = A' k
    f32x2 a0 = {0,0}, a1 = {0,0}, a2 = {0,0}, a3 = {0,0};
    #pragma unroll
    for (int j = 0; j < 8; ++j) {
      a0 = pkfma(A[j],      sk[j],      a0);
      a1 = pkfma(A[j + 8],  sk[j + 8],  a1);
      a2 = pkfma(A[j + 16], sk[j + 16], a2);
      a3 = pkfma(A[j + 24], sk[j + 24], a3);
    }
    a0 += a1; a2 += a3; a0 += a2;
    float ai = a0.x + a0.y;
    __syncthreads();
    // K update (after b)
    f32x2 kl2 = {kl, kl};
    #pragma unroll
    for (int j = 0; j < 32; ++j) Kr[j] = pkfma(kl2, sk[j], Kr[j]);
    // d = A' b  (b broadcast via LDS; A not yet updated)
    const f32x2* bbp = (const f32x2*)&bbuf[(t & 1) << 6];
    f32x2 d0 = {0,0}, d1 = {0,0}, d2 = {0,0}, d3 = {0,0};
    #pragma unroll
    for (int j = 0; j < 8; ++j) {
      d0 = pkfma(A[j],      bbp[j],      d0);
      d1 = pkfma(A[j + 8],  bbp[j + 8],  d1);
      d2 = pkfma(A[j + 16], bbp[j + 16], d2);
      d3 = pkfma(A[j + 24], bbp[j + 24], d3);
    }
    d0 += d1; d2 += d3; d0 += d2;
    float di = d0.x + d0.y;
    // A update
    f32x2 vl2 = {vl, vl};
    #pragma unroll
    for (int j = 0; j < 32; ++j) A[j] = pkfma(vl2, sk[j], A[j]);
    // per-lane partial invariants
    float r1 = vl * ai;                       // contributes to v.a
    pF = fmaf(2.f, r1, pF);
    pF = fmaf(m0, ka * nv, pF);
    float r2 = fmaf(2.f * vl, di, ai * ai);   // 2 v.d + ||a||^2 parts
    r2 = fmaf(2.f * ka, r1, r2);              // 2 kappa (v.a)
    r2 = fmaf(nv * kl, bi, r2);               // nu (k.b)
    r2 = fmaf(m0, ka * ka * nv, r2);          // kappa^2 nu (uniform, lane0)
    pT += r2;
    pS = fmaf(m0, nv, pS);
    float tt = (float)(c * CC + t + 1);
    float inv = 1.0f / tt;
    float out = inv * (0.5f * pS + inv * fmaf(0.5f * inv, pT, -pF));
    op[t * 64] = out;
  }
}

// K4: reduce 64 per-lane partials -> one cost per token
__global__ __launch_bounds__(256) void k4_reduce(const float* __restrict__ ws,
                                                 float* __restrict__ out) {
  int wid = (blockIdx.x * 256 + threadIdx.x) >> 6;
  int lane = threadIdx.x & 63;
  float x = ws[OFF_OUTP + (size_t)wid * 64 + lane];
  #pragma unroll
  for (int m = 1; m < 64; m <<= 1) x += __shfl_xor(x, m, 64);
  if (lane == 0) out[wid] = x;
}

extern "C" void kernel_launch(void* const* d_in, const int* in_sizes, int n_in,
                              void* d_out, int out_size, void* d_ws, size_t ws_size,
                              hipStream_t stream) {
  const float* k = (const float*)d_in[1];
  const float* v = (const float*)d_in[2];
  float* out = (float*)d_out;
  float* ws = (float*)d_ws;
  hipLaunchKernelGGL(k0_kapnu,  dim3(BB * LL / 4), dim3(256), 0, stream, k, v, ws);
  hipLaunchKernelGGL(k1_partial, dim3(BB * NCH),   dim3(256), 0, stream, k, v, ws);
  hipLaunchKernelGGL(k2_prefix, dim3(BB * 8192 / 256), dim3(256), 0, stream, ws);
  hipLaunchKernelGGL(k2b_t0,    dim3(BB * NCH),    dim3(256), 0, stream, ws);
  hipLaunchKernelGGL(k3_scan,   dim3(BB * NCH),    dim3(64),  0, stream, k, v, ws);
  hipLaunchKernelGGL(k4_reduce, dim3(BB * LL / 4), dim3(256), 0, stream, ws, out);
}

// Round 2
// 111.446 us; speedup vs baseline: 1.0433x; 1.0433x over previous
//
#include <hip/hip_runtime.h>

#define BB 8
#define LL 2048

typedef float f32x2 __attribute__((ext_vector_type(2)));
typedef float f32x4 __attribute__((ext_vector_type(4)));

static __device__ __forceinline__ f32x2 pkfma(f32x2 a, f32x2 b, f32x2 c) {
  return __builtin_elementwise_fma(a, b, c);
}
static __device__ __forceinline__ f32x4 ffma(f32x4 a, f32x4 b, f32x4 c) {
  return __builtin_elementwise_fma(a, b, c);
}

// K0: per-token kappa = ||k||^2, nu = ||v||^2  (one wave per token)
__global__ __launch_bounds__(256) void k0_kapnu(const float* __restrict__ k,
                                                const float* __restrict__ v,
                                                float* __restrict__ kap,
                                                float* __restrict__ nu) {
  int wid = (blockIdx.x * 256 + threadIdx.x) >> 6;
  int lane = threadIdx.x & 63;
  float kk = k[(size_t)wid * 64 + lane];
  float vv = v[(size_t)wid * 64 + lane];
  float pk = kk * kk, pv = vv * vv;
  #pragma unroll
  for (int m = 1; m < 64; m <<= 1) {
    pk += __shfl_xor(pk, m, 64);
    pv += __shfl_xor(pv, m, 64);
  }
  if (lane == 0) {
    kap[wid] = pk;
    nu[wid] = pv;
  }
}

// K1: per-chunk partial sums of v k^T and k k^T. 4 waves, wave w owns cols [16w,16w+16).
template<int CC_>
__global__ __launch_bounds__(256) void k1_partial(const float* __restrict__ k,
                                                  const float* __restrict__ v,
                                                  float* __restrict__ pref_all) {
  constexpr int NCH_ = LL / CC_;
  int s = blockIdx.x / NCH_, c = blockIdx.x % NCH_;
  int tid = threadIdx.x;
  int lane = tid & 63;
  int j0 = __builtin_amdgcn_readfirstlane((tid >> 6) * 16);
  const float* kb = k + (size_t)(s * LL + c * CC_) * 64;
  const float* vb = v + (size_t)(s * LL + c * CC_) * 64;
  f32x4 accA[4] = {}, accK[4] = {};
  for (int t = 0; t < CC_; ++t) {
    const float* kr = kb + t * 64;
    float vl = vb[t * 64 + lane];
    float kl = kr[lane];
    f32x4 vl4 = {vl, vl, vl, vl}, kl4 = {kl, kl, kl, kl};
    #pragma unroll
    for (int e = 0; e < 4; ++e) {
      f32x4 sk = *(const f32x4*)(kr + j0 + 4 * e);
      accA[e] = ffma(vl4, sk, accA[e]);
      accK[e] = ffma(kl4, sk, accK[e]);
    }
  }
  float* dst = pref_all + (size_t)(s * NCH_ + c) * 8192;
  #pragma unroll
  for (int e = 0; e < 4; ++e) {
    *(f32x4*)(dst + lane * 64 + j0 + 4 * e) = accA[e];
    *(f32x4*)(dst + 4096 + lane * 64 + j0 + 4 * e) = accK[e];
  }
}

// K2: in-place exclusive prefix over chunks, 8-wide load batching to hide latency
template<int NCH_>
__global__ __launch_bounds__(256) void k2_prefix(float* __restrict__ pref_all) {
  int gid = blockIdx.x * 256 + threadIdx.x;   // [0, BB*8192)
  int s = gid >> 13, e = gid & 8191;
  float* base = pref_all + (size_t)s * NCH_ * 8192 + e;
  float acc = 0.f;
  for (int cb = 0; cb < NCH_; cb += 8) {
    float x[8];
    #pragma unroll
    for (int u = 0; u < 8; ++u) x[u] = base[(size_t)(cb + u) * 8192];
    #pragma unroll
    for (int u = 0; u < 8; ++u) {
      base[(size_t)(cb + u) * 8192] = acc;
      acc += x[u];
    }
  }
}

// K2b: per-(s,c) chunk-start scalars T0 = Tr(A0 K0 A0^T), s0 = sum of nu before chunk
template<int CC_>
__global__ __launch_bounds__(256) void k2b_t0(const float* __restrict__ pref_all,
                                              const float* __restrict__ nu_all,
                                              float* __restrict__ t0_all) {
  constexpr int NCH_ = LL / CC_;
  int s = blockIdx.x / NCH_, c = blockIdx.x % NCH_;
  int tid = threadIdx.x, lane = tid & 63;
  int j0 = __builtin_amdgcn_readfirstlane((tid >> 6) * 16);
  const float* pref = pref_all + (size_t)(s * NCH_ + c) * 8192;
  f32x2 Ar[32];
  #pragma unroll
  for (int j = 0; j < 32; ++j) Ar[j] = *(const f32x2*)(pref + lane * 64 + 2 * j);
  f32x2 acc[8] = {};
  #pragma unroll
  for (int m = 0; m < 64; ++m) {
    float am = (m & 1) ? Ar[m >> 1].y : Ar[m >> 1].x;
    f32x2 am2 = {am, am};
    const float* krow = pref + 4096 + m * 64 + j0;   // wave-uniform
    #pragma unroll
    for (int e = 0; e < 8; ++e)
      acc[e] = pkfma(am2, *(const f32x2*)(krow + 2 * e), acc[e]);
  }
  f32x2 tp2 = {0, 0};
  #pragma unroll
  for (int e = 0; e < 8; ++e) {
    f32x2 arr = *(const f32x2*)(pref + lane * 64 + j0 + 2 * e);
    tp2 = pkfma(acc[e], arr, tp2);
  }
  float t0p = tp2.x + tp2.y;
  float s0p = 0.f;
  const float* nub = nu_all + s * LL;
  for (int t = tid; t < c * CC_; t += 256) s0p += nub[t];
  #pragma unroll
  for (int m = 1; m < 64; m <<= 1) {
    t0p += __shfl_xor(t0p, m, 64);
    s0p += __shfl_xor(s0p, m, 64);
  }
  __shared__ float red[8];
  if (lane == 0) { red[(tid >> 6) * 2] = t0p; red[(tid >> 6) * 2 + 1] = s0p; }
  __syncthreads();
  if (tid == 0) {
    t0_all[(s * NCH_ + c) * 2]     = red[0] + red[2] + red[4] + red[6];
    t0_all[(s * NCH_ + c) * 2 + 1] = red[1] + red[3] + red[5] + red[7];
  }
}

// K3: sequential scan over one CC_-token chunk. One wave; lane i owns row i of A and K.
// No barriers (single wave; same-wave DS ops are in-order). Software-pipelined:
// next-token k-row + scalars are loaded early (global->reg), k-row staged to the
// other LDS buffer late (T14 issue-early/write-late).
template<int CC_>
__global__ __launch_bounds__(64, 1) void k3_scan(const float* __restrict__ k,
                                                 const float* __restrict__ v,
                                                 const float* __restrict__ pref_all,
                                                 const float* __restrict__ kap_all,
                                                 const float* __restrict__ nu_all,
                                                 const float* __restrict__ t0_all,
                                                 float* __restrict__ out) {
  constexpr int NCH_ = LL / CC_;
  int s = blockIdx.x / NCH_, c = blockIdx.x % NCH_;
  int lane = threadIdx.x;
  __shared__ float kbuf[2][64];
  __shared__ float bbuf[64];
  const float* pref = pref_all + (size_t)(s * NCH_ + c) * 8192;
  f32x4 A[16], K[16];
  #pragma unroll
  for (int j = 0; j < 16; ++j) A[j] = *(const f32x4*)(pref + lane * 64 + 4 * j);
  #pragma unroll
  for (int j = 0; j < 16; ++j) K[j] = *(const f32x4*)(pref + 4096 + lane * 64 + 4 * j);
  f32x4 f4 = {};
  #pragma unroll
  for (int j = 0; j < 16; ++j) f4 = ffma(A[j], A[j], f4);
  float pF = (f4.x + f4.y) + (f4.z + f4.w);
  float T0 = t0_all[(s * NCH_ + c) * 2];
  float S0 = t0_all[(s * NCH_ + c) * 2 + 1];
  float m0 = (lane == 0) ? 1.f : 0.f;
  float pT = m0 * T0;
  float pS = m0 * S0;
  const float* kb  = k + (size_t)(s * LL + c * CC_) * 64;
  const float* vb  = v + (size_t)(s * LL + c * CC_) * 64;
  const float* kap = kap_all + s * LL + c * CC_;
  const float* nuv = nu_all  + s * LL + c * CC_;
  int tok0 = s * LL + c * CC_;
  // prologue: stage token 0
  kbuf[0][lane] = kb[lane];
  float vl_c = vb[lane];
  float ka_c = kap[0], nv_c = nuv[0];

  #pragma unroll 2
  for (int t = 0; t < CC_; ++t) {
    int buf = t & 1;
    // issue next-token loads early (clamped index keeps them in-bounds; unused on last iter)
    int tn = (t + 1 < CC_) ? t + 1 : t;
    float kn_n = kb[tn * 64 + lane];
    float vl_n = vb[tn * 64 + lane];
    float ka_n = kap[tn];
    float nv_n = nuv[tn];
    // k_t broadcast from LDS (uniform b128 reads)
    f32x4 sk[16];
    #pragma unroll
    for (int j = 0; j < 16; ++j) sk[j] = *(const f32x4*)&kbuf[buf][4 * j];
    float kl = kbuf[buf][lane];
    // b = K' k
    f32x4 b0 = {}, b1 = {}, b2 = {}, b3 = {};
    #pragma unroll
    for (int j = 0; j < 4; ++j) {
      b0 = ffma(K[j],      sk[j],      b0);
      b1 = ffma(K[j + 4],  sk[j + 4],  b1);
      b2 = ffma(K[j + 8],  sk[j + 8],  b2);
      b3 = ffma(K[j + 12], sk[j + 12], b3);
    }
    b0 += b1; b2 += b3; b0 += b2;
    float bi = (b0.x + b0.y) + (b0.z + b0.w);
    bbuf[lane] = bi;
    // a = A' k
    f32x4 a0 = {}, a1 = {}, a2 = {}, a3 = {};
    #pragma unroll
    for (int j = 0; j < 4; ++j) {
      a0 = ffma(A[j],      sk[j],      a0);
      a1 = ffma(A[j + 4],  sk[j + 4],  a1);
      a2 = ffma(A[j + 8],  sk[j + 8],  a2);
      a3 = ffma(A[j + 12], sk[j + 12], a3);
    }
    a0 += a1; a2 += a3; a0 += a2;
    float ai = (a0.x + a0.y) + (a0.z + a0.w);
    // K update (covers LDS write->read latency of bbuf)
    f32x4 kl4 = {kl, kl, kl, kl};
    #pragma unroll
    for (int j = 0; j < 16; ++j) K[j] = ffma(kl4, sk[j], K[j]);
    // stage next k row into the other buffer (write-late)
    kbuf[buf ^ 1][lane] = kn_n;
    // d = A' b (b broadcast via LDS, uniform b128 reads; A pre-update)
    f32x4 d0 = {}, d1 = {}, d2 = {}, d3 = {};
    #pragma unroll
    for (int j = 0; j < 4; ++j) {
      d0 = ffma(A[j],      *(const f32x4*)&bbuf[4 * j],        d0);
      d1 = ffma(A[j + 4],  *(const f32x4*)&bbuf[4 * (j + 4)],  d1);
      d2 = ffma(A[j + 8],  *(const f32x4*)&bbuf[4 * (j + 8)],  d2);
      d3 = ffma(A[j + 12], *(const f32x4*)&bbuf[4 * (j + 12)], d3);
    }
    d0 += d1; d2 += d3; d0 += d2;
    float di = (d0.x + d0.y) + (d0.z + d0.w);
    // A update
    f32x4 vl4 = {vl_c, vl_c, vl_c, vl_c};
    #pragma unroll
    for (int j = 0; j < 16; ++j) A[j] = ffma(vl4, sk[j], A[j]);
    // per-lane partial invariants
    float r1 = vl_c * ai;                       // v.a contribution
    pF = fmaf(2.f, r1, pF);
    pF = fmaf(m0, ka_c * nv_c, pF);
    float r2 = fmaf(2.f * vl_c, di, ai * ai);   // 2 v.d + ||a||^2 parts
    r2 = fmaf(2.f * ka_c, r1, r2);              // 2 kappa (v.a)
    r2 = fmaf(nv_c * kl, bi, r2);               // nu (k.b)
    r2 = fmaf(m0, ka_c * ka_c * nv_c, r2);      // kappa^2 nu (uniform, lane0)
    pT += r2;
    pS = fmaf(m0, nv_c, pS);
    float tt = (float)(c * CC_ + t + 1);
    float inv = 1.0f / tt;
    float o = inv * (0.5f * pS + inv * fmaf(0.5f * inv, pT, -pF));
    // in-wave reduce + store (off the critical path of the next iteration)
    #pragma unroll
    for (int m = 1; m < 64; m <<= 1) o += __shfl_xor(o, m, 64);
    if (lane == 0) out[tok0 + t] = o;
    // rotate prefetched scalars
    vl_c = vl_n; ka_c = ka_n; nv_c = nv_n;
  }
}

template<int CC_>
static void launch_all(const float* k, const float* v, float* ws, float* out,
                       hipStream_t stream) {
  constexpr int NCH_ = LL / CC_;
  float* pref = ws;
  float* kap = ws + (size_t)BB * NCH_ * 8192;
  float* nu  = kap + BB * LL;
  float* t0  = nu + BB * LL;
  hipLaunchKernelGGL(k0_kapnu, dim3(BB * LL / 4), dim3(256), 0, stream, k, v, kap, nu);
  hipLaunchKernelGGL(k1_partial<CC_>, dim3(BB * NCH_), dim3(256), 0, stream, k, v, pref);
  hipLaunchKernelGGL(k2_prefix<NCH_>, dim3(BB * 8192 / 256), dim3(256), 0, stream, pref);
  hipLaunchKernelGGL(k2b_t0<CC_>, dim3(BB * NCH_), dim3(256), 0, stream, pref, nu, t0);
  hipLaunchKernelGGL(k3_scan<CC_>, dim3(BB * NCH_), dim3(64), 0, stream,
                     k, v, pref, kap, nu, t0, out);
}

extern "C" void kernel_launch(void* const* d_in, const int* in_sizes, int n_in,
                              void* d_out, int out_size, void* d_ws, size_t ws_size,
                              hipStream_t stream) {
  const float* k = (const float*)d_in[1];
  const float* v = (const float*)d_in[2];
  float* out = (float*)d_out;
  float* ws = (float*)d_ws;
  auto need = [](int cc) {
    size_t nch = LL / cc;
    return ((size_t)BB * nch * 8192 + 2ull * BB * LL + (size_t)BB * nch * 2) * 4;
  };
  if (ws_size >= need(16))      launch_all<16>(k, v, ws, out, stream);
  else if (ws_size >= need(32)) launch_all<32>(k, v, ws, out, stream);
  else                          launch_all<64>(k, v, ws, out, stream);
}

// Round 3
// 65.834 us; speedup vs baseline: 1.7661x; 1.6929x over previous
//
#include <hip/hip_runtime.h>

#define BB 8
#define LL 2048

typedef float f32x4 __attribute__((ext_vector_type(4)));

static __device__ __forceinline__ f32x4 ffma(f32x4 a, f32x4 b, f32x4 c) {
  return __builtin_elementwise_fma(a, b, c);
}

// ws layout (floats): pref[BB*NCH*8192] | kap[BB*LL] | nu[BB*LL] | dT[BB*NCH]

// K1: per-chunk partial sums of v k^T and k k^T, plus per-token kappa/nu.
// 4 waves; wave w owns cols [16w,16w+16) for the outer products; tokens are
// split across waves for the kappa/nu reductions (rows are L1-warm).
template<int CC_>
__global__ __launch_bounds__(256) void k1_partial(const float* __restrict__ k,
                                                  const float* __restrict__ v,
                                                  float* __restrict__ pref_all,
                                                  float* __restrict__ kap,
                                                  float* __restrict__ nu) {
  constexpr int NCH_ = LL / CC_;
  int s = blockIdx.x / NCH_, c = blockIdx.x % NCH_;
  int tid = threadIdx.x;
  int lane = tid & 63, w = tid >> 6;
  int j0 = __builtin_amdgcn_readfirstlane(w * 16);
  int tok0 = s * LL + c * CC_;
  const float* kb = k + (size_t)tok0 * 64;
  const float* vb = v + (size_t)tok0 * 64;
  f32x4 accA[4] = {}, accK[4] = {};
  for (int t = 0; t < CC_; ++t) {
    const float* kr = kb + t * 64;
    float vl = vb[t * 64 + lane];
    float kl = kr[lane];
    f32x4 vl4 = {vl, vl, vl, vl}, kl4 = {kl, kl, kl, kl};
    #pragma unroll
    for (int e = 0; e < 4; ++e) {
      f32x4 sk = *(const f32x4*)(kr + j0 + 4 * e);
      accA[e] = ffma(vl4, sk, accA[e]);
      accK[e] = ffma(kl4, sk, accK[e]);
    }
  }
  float* dst = pref_all + (size_t)(s * NCH_ + c) * 8192;
  #pragma unroll
  for (int e = 0; e < 4; ++e) {
    *(f32x4*)(dst + lane * 64 + j0 + 4 * e) = accA[e];
    *(f32x4*)(dst + 4096 + lane * 64 + j0 + 4 * e) = accK[e];
  }
  // kappa/nu: wave w handles tokens w, w+4, ... (rows are in L1 now)
  for (int t = w; t < CC_; t += 4) {
    float kl = kb[t * 64 + lane];
    float vl = vb[t * 64 + lane];
    float pk = kl * kl, pv = vl * vl;
    #pragma unroll
    for (int m = 1; m < 64; m <<= 1) {
      pk += __shfl_xor(pk, m, 64);
      pv += __shfl_xor(pv, m, 64);
    }
    if (lane == 0) {
      kap[tok0 + t] = pk;
      nu[tok0 + t] = pv;
    }
  }
}

// K2: in-place exclusive prefix over chunks; 8-wide batches with next-batch prefetch
template<int NCH_>
__global__ __launch_bounds__(256) void k2_prefix(float* __restrict__ pref_all) {
  int gid = blockIdx.x * 256 + threadIdx.x;   // [0, BB*8192)
  int s = gid >> 13, e = gid & 8191;
  float* base = pref_all + (size_t)s * NCH_ * 8192 + e;
  float x[8];
  #pragma unroll
  for (int u = 0; u < 8; ++u) x[u] = base[(size_t)u * 8192];
  float acc = 0.f;
  #pragma unroll
  for (int cb = 0; cb < NCH_; cb += 8) {
    float y[8];
    if (cb + 8 < NCH_) {
      #pragma unroll
      for (int u = 0; u < 8; ++u) y[u] = base[(size_t)(cb + 8 + u) * 8192];
    }
    #pragma unroll
    for (int u = 0; u < 8; ++u) {
      float t = x[u];
      base[(size_t)(cb + u) * 8192] = acc;
      acc += t;
    }
    #pragma unroll
    for (int u = 0; u < 8; ++u) x[u] = y[u];
  }
}

// K3: sequential scan over one CC_-token chunk. One wave; lane i owns row i of
// A (sum v k^T) and K (sum k k^T). Seedless: emits per-chunk dT and partial out
// (missing the S0/T0 linear terms, added by K4).
template<int CC_>
__global__ __launch_bounds__(64, 1) void k3_scan(const float* __restrict__ k,
                                                 const float* __restrict__ v,
                                                 const float* __restrict__ pref_all,
                                                 const float* __restrict__ kap_all,
                                                 const float* __restrict__ nu_all,
                                                 float* __restrict__ dT,
                                                 float* __restrict__ out) {
  constexpr int NCH_ = LL / CC_;
  int s = blockIdx.x / NCH_, c = blockIdx.x % NCH_;
  int lane = threadIdx.x;
  __shared__ float kbuf[2][64];
  __shared__ float bbuf[64];
  const float* pref = pref_all + (size_t)(s * NCH_ + c) * 8192;
  f32x4 A[16], K[16];
  #pragma unroll
  for (int j = 0; j < 16; ++j) A[j] = *(const f32x4*)(pref + lane * 64 + 4 * j);
  #pragma unroll
  for (int j = 0; j < 16; ++j) K[j] = *(const f32x4*)(pref + 4096 + lane * 64 + 4 * j);
  f32x4 f4 = {};
  #pragma unroll
  for (int j = 0; j < 16; ++j) f4 = ffma(A[j], A[j], f4);
  float pF = (f4.x + f4.y) + (f4.z + f4.w);   // per-lane ||A0 row||^2 (sums to F0)
  float m0 = (lane == 0) ? 1.f : 0.f;
  float pT = 0.f;                             // chunk-local trace increment partials
  int tok0 = s * LL + c * CC_;
  const float* kb  = k + (size_t)tok0 * 64;
  const float* vb  = v + (size_t)tok0 * 64;
  const float* kap = kap_all + tok0;
  const float* nuv = nu_all  + tok0;
  // prologue: stage token 0
  kbuf[0][lane] = kb[lane];
  float vl_c = vb[lane];
  float ka_c = kap[0], nv_c = nuv[0];

  #pragma unroll 2
  for (int t = 0; t < CC_; ++t) {
    int buf = t & 1;
    // issue next-token loads early
    int tn = (t + 1 < CC_) ? t + 1 : t;
    float kn_n = kb[tn * 64 + lane];
    float vl_n = vb[tn * 64 + lane];
    float ka_n = kap[tn];
    float nv_n = nuv[tn];
    // k_t broadcast from LDS (uniform b128 reads)
    f32x4 sk[16];
    #pragma unroll
    for (int j = 0; j < 16; ++j) sk[j] = *(const f32x4*)&kbuf[buf][4 * j];
    float kl = kbuf[buf][lane];
    // b = K' k
    f32x4 b0 = {}, b1 = {}, b2 = {}, b3 = {};
    #pragma unroll
    for (int j = 0; j < 4; ++j) {
      b0 = ffma(K[j],      sk[j],      b0);
      b1 = ffma(K[j + 4],  sk[j + 4],  b1);
      b2 = ffma(K[j + 8],  sk[j + 8],  b2);
      b3 = ffma(K[j + 12], sk[j + 12], b3);
    }
    b0 += b1; b2 += b3; b0 += b2;
    float bi = (b0.x + b0.y) + (b0.z + b0.w);
    bbuf[lane] = bi;
    // a = A' k
    f32x4 a0 = {}, a1 = {}, a2 = {}, a3 = {};
    #pragma unroll
    for (int j = 0; j < 4; ++j) {
      a0 = ffma(A[j],      sk[j],      a0);
      a1 = ffma(A[j + 4],  sk[j + 4],  a1);
      a2 = ffma(A[j + 8],  sk[j + 8],  a2);
      a3 = ffma(A[j + 12], sk[j + 12], a3);
    }
    a0 += a1; a2 += a3; a0 += a2;
    float ai = (a0.x + a0.y) + (a0.z + a0.w);
    // K update (covers bbuf write->read latency)
    f32x4 kl4 = {kl, kl, kl, kl};
    #pragma unroll
    for (int j = 0; j < 16; ++j) K[j] = ffma(kl4, sk[j], K[j]);
    // stage next k row (write-late)
    kbuf[buf ^ 1][lane] = kn_n;
    // d = A' b (b broadcast via LDS; A pre-update)
    f32x4 d0 = {}, d1 = {}, d2 = {}, d3 = {};
    #pragma unroll
    for (int j = 0; j < 4; ++j) {
      d0 = ffma(A[j],      *(const f32x4*)&bbuf[4 * j],        d0);
      d1 = ffma(A[j + 4],  *(const f32x4*)&bbuf[4 * (j + 4)],  d1);
      d2 = ffma(A[j + 8],  *(const f32x4*)&bbuf[4 * (j + 8)],  d2);
      d3 = ffma(A[j + 12], *(const f32x4*)&bbuf[4 * (j + 12)], d3);
    }
    d0 += d1; d2 += d3; d0 += d2;
    float di = (d0.x + d0.y) + (d0.z + d0.w);
    // A update
    f32x4 vl4 = {vl_c, vl_c, vl_c, vl_c};
    #pragma unroll
    for (int j = 0; j < 16; ++j) A[j] = ffma(vl4, sk[j], A[j]);
    // per-lane partial invariants
    float r1 = vl_c * ai;                       // v.a contribution
    pF = fmaf(2.f, r1, pF);
    pF = fmaf(m0, ka_c * nv_c, pF);
    float r2 = fmaf(2.f * vl_c, di, ai * ai);   // 2 v.d + ||a||^2 parts
    r2 = fmaf(2.f * ka_c, r1, r2);              // 2 kappa (v.a)
    r2 = fmaf(nv_c * kl, bi, r2);               // nu (k.b)
    r2 = fmaf(m0, ka_c * ka_c * nv_c, r2);      // kappa^2 nu (lane0)
    pT += r2;
    float tt = (float)(c * CC_ + t + 1);
    float inv = 1.0f / tt;
    float o = inv * (inv * fmaf(0.5f * inv, pT, -pF));   // partial (no S0/T0 terms)
    #pragma unroll
    for (int m = 1; m < 64; m <<= 1) o += __shfl_xor(o, m, 64);
    if (lane == 0) out[tok0 + t] = o;
    vl_c = vl_n; ka_c = ka_n; nv_c = nv_n;
  }
  // chunk trace increment
  #pragma unroll
  for (int m = 1; m < 64; m <<= 1) pT += __shfl_xor(pT, m, 64);
  if (lane == 0) dT[s * NCH_ + c] = pT;
}

// K4: per-stream (8 blocks): exclusive chunk-prefix of dT -> T0; inclusive
// nu-prefix over tokens -> s_tau; out[t] += 0.5*s_tau/tau + 0.5*T0/tau^3.
template<int CC_>
__global__ __launch_bounds__(256) void k4_fix(const float* __restrict__ dT,
                                              const float* __restrict__ nu,
                                              float* __restrict__ out) {
  constexpr int NCH_ = LL / CC_;
  int s = blockIdx.x;
  int tid = threadIdx.x, lane = tid & 63, w = tid >> 6;
  __shared__ float T0s[NCH_];
  __shared__ float wsum[4];
  // phase A: chunk-delta exclusive prefix on wave 0
  if (w == 0) {
    constexpr int PER = (NCH_ >= 64) ? NCH_ / 64 : 1;
    float loc[PER];
    float tot = 0.f;
    #pragma unroll
    for (int u = 0; u < PER; ++u) {
      int c = lane * PER + u;
      loc[u] = (c < NCH_) ? dT[s * NCH_ + c] : 0.f;
      tot += loc[u];
    }
    float incl = tot;
    #pragma unroll
    for (int off = 1; off < 64; off <<= 1) {
      float n = __shfl_up(incl, off, 64);
      if (lane >= off) incl += n;
    }
    float run = incl - tot;   // exclusive base for this lane
    #pragma unroll
    for (int u = 0; u < PER; ++u) {
      int c = lane * PER + u;
      if (c < NCH_) T0s[c] = run;
      run += loc[u];
    }
  }
  __syncthreads();
  // phase B: inclusive nu prefix over LL tokens; 8 contiguous per thread
  const float* nus = nu + s * LL;
  float p[8];
  {
    float run = 0.f;
    #pragma unroll
    for (int u = 0; u < 8; ++u) {
      run += nus[tid * 8 + u];
      p[u] = run;
    }
  }
  float tot = p[7];
  float incl = tot;
  #pragma unroll
  for (int off = 1; off < 64; off <<= 1) {
    float n = __shfl_up(incl, off, 64);
    if (lane >= off) incl += n;
  }
  if (lane == 63) wsum[w] = incl;
  __syncthreads();
  float wbase = 0.f;
  for (int i = 0; i < w; ++i) wbase += wsum[i];
  float base = wbase + incl - tot;   // exclusive prefix for this thread's first token
  // phase C: apply corrections
  float* os = out + s * LL;
  #pragma unroll
  for (int u = 0; u < 8; ++u) {
    int t = tid * 8 + u;
    float tau = (float)(t + 1);
    float inv = 1.0f / tau;
    float sincl = base + p[u];
    float t0 = T0s[t / CC_];
    float add = fmaf(0.5f * inv, sincl, 0.5f * inv * inv * inv * t0);
    os[t] += add;
  }
}

template<int CC_>
static void launch_all(const float* k, const float* v, float* ws, float* out,
                       hipStream_t stream) {
  constexpr int NCH_ = LL / CC_;
  float* pref = ws;
  float* kap = ws + (size_t)BB * NCH_ * 8192;
  float* nu  = kap + BB * LL;
  float* dT  = nu + BB * LL;
  hipLaunchKernelGGL(k1_partial<CC_>, dim3(BB * NCH_), dim3(256), 0, stream, k, v, pref, kap, nu);
  hipLaunchKernelGGL(k2_prefix<NCH_>, dim3(BB * 8192 / 256), dim3(256), 0, stream, pref);
  hipLaunchKernelGGL(k3_scan<CC_>, dim3(BB * NCH_), dim3(64), 0, stream, k, v, pref, kap, nu, dT, out);
  hipLaunchKernelGGL(k4_fix<CC_>, dim3(BB), dim3(256), 0, stream, dT, nu, out);
}

extern "C" void kernel_launch(void* const* d_in, const int* in_sizes, int n_in,
                              void* d_out, int out_size, void* d_ws, size_t ws_size,
                              hipStream_t stream) {
  const float* k = (const float*)d_in[1];
  const float* v = (const float*)d_in[2];
  float* out = (float*)d_out;
  float* ws = (float*)d_ws;
  auto need = [](int cc) {
    size_t nch = LL / cc;
    return ((size_t)BB * nch * 8192 + 2ull * BB * LL + (size_t)BB * nch) * 4;
  };
  if (ws_size >= need(32))      launch_all<32>(k, v, ws, out, stream);
  else                          launch_all<64>(k, v, ws, out, stream);
}